// Round 6
// baseline (795.255 us; speedup 1.0000x reference)
//
#include <hip/hip_runtime.h>
#include <stdint.h>

typedef int v8i __attribute__((ext_vector_type(8)));
typedef float f32x4 __attribute__((ext_vector_type(4)));

#define NROWS 8192
#define DIM   1024
#define BK    128
#define NKT   (DIM / BK)   // 8
#define MARGIN 0.3f

// async global->LDS, 16B per lane; LDS dest = wave-uniform base + lane*16
#define GLOAD_LDS16(gp, lp)                                                    \
  __builtin_amdgcn_global_load_lds(                                            \
      (const __attribute__((address_space(1))) void*)(gp),                     \
      (__attribute__((address_space(3))) void*)(lp), 16, 0, 0)

// fp32 [8192*1024] -> fp8 e4m3 (OCP, v_cvt_pk_fp8_f32); 16 elems/thread.
// Also zeroes the scalar output.
__global__ __launch_bounds__(256) void cvt_f32_fp8(const float* __restrict__ in,
                                                   uint8_t* __restrict__ out,
                                                   float* __restrict__ loss) {
  if (blockIdx.x == 0 && threadIdx.x == 0) loss[0] = 0.0f;
  size_t i = ((size_t)blockIdx.x * 256 + threadIdx.x) * 16;
  float4 v0 = *(const float4*)(in + i);
  float4 v1 = *(const float4*)(in + i + 4);
  float4 v2 = *(const float4*)(in + i + 8);
  float4 v3 = *(const float4*)(in + i + 12);
  int w0 = 0, w1 = 0, w2 = 0, w3 = 0;
  w0 = __builtin_amdgcn_cvt_pk_fp8_f32(v0.x, v0.y, w0, false);
  w0 = __builtin_amdgcn_cvt_pk_fp8_f32(v0.z, v0.w, w0, true);
  w1 = __builtin_amdgcn_cvt_pk_fp8_f32(v1.x, v1.y, w1, false);
  w1 = __builtin_amdgcn_cvt_pk_fp8_f32(v1.z, v1.w, w1, true);
  w2 = __builtin_amdgcn_cvt_pk_fp8_f32(v2.x, v2.y, w2, false);
  w2 = __builtin_amdgcn_cvt_pk_fp8_f32(v2.z, v2.w, w2, true);
  w3 = __builtin_amdgcn_cvt_pk_fp8_f32(v3.x, v3.y, w3, false);
  w3 = __builtin_amdgcn_cvt_pk_fp8_f32(v3.z, v3.w, w3, true);
  uint4 p; p.x = (unsigned)w0; p.y = (unsigned)w1; p.z = (unsigned)w2; p.w = (unsigned)w3;
  *(uint4*)(out + i) = p;
}

// One block = one 128x128 tile of sim = A*A^T (upper triangle, bi<=bj).
// MX-fp8 path (m148-validated): mfma_scale_f32_16x16x128_f8f6f4 with unit
// scales (e8m0 0x7F = 1.0) == plain e4m3 matmul at 2x bf16 MFMA rate.
// BK=128 -> 8 K-iterations (half the barrier-drain events), 8 staging loads
// in flight per wave per step (2x MLP vs bf16 version), half the bytes.
//
// LDS tile [128 rows][128 B]; slot permutation: row r, 16B-slot c holds
// global col-group c ^ (r&7) (applied on the GLOBAL source address, since
// global_load_lds pins slot = lane*16B). Fragment b128 reads then hit each
// bank-group 2x = free aliasing.
__global__ __launch_bounds__(256, 3) void gram_loss(const uint8_t* __restrict__ A8,
                                                    const int* __restrict__ targets,
                                                    float* __restrict__ out) {
  __shared__ uint8_t As[128 * 128];   // 16 KB
  __shared__ uint8_t Bs[128 * 128];   // 16 KB
  __shared__ int tRow[128];
  __shared__ int tCol[128];
  __shared__ float wsum[4];

  // linear block id -> (bi, bj) with 0 <= bi <= bj < 64  (fp32 guess + exact fixup)
  int t = blockIdx.x;
  int bi = (int)(0.5f * (129.0f - __builtin_sqrtf(129.0f * 129.0f - 8.0f * (float)t)));
  if (bi < 0) bi = 0;
  if (bi > 63) bi = 63;
  while (bi < 63 && ((bi + 1) * (129 - (bi + 1))) / 2 <= t) ++bi;
  while (bi > 0 && (bi * (129 - bi)) / 2 > t) --bi;
  int bj = bi + (t - (bi * (129 - bi)) / 2);

  const int iBase = bi * 128;
  const int jBase = bj * 128;

  const int tid  = threadIdx.x;
  const int wave = tid >> 6;
  const int lane = tid & 63;

  if (tid < 128) tRow[tid] = targets[iBase + tid];
  else           tCol[tid - 128] = targets[jBase + tid - 128];

  // staging: wave w stages rows [w*32, w*32+32) of both tiles, 4 loads each.
  // one load = 64 lanes x 16B = 8 rows x 128B; lane -> row w*32+l*8+(lane>>3),
  // swizzled global col-group (lane&7) ^ (lane>>3).
  const int lrow = lane >> 3;                 // 0..7
  const int cg   = (lane & 7) ^ lrow;         // swizzled source col-group
  const uint8_t* gA = A8 + (size_t)(iBase + wave * 32 + lrow) * DIM + cg * 16;
  const uint8_t* gB = A8 + (size_t)(jBase + wave * 32 + lrow) * DIM + cg * 16;
  uint8_t* lA = &As[wave * 32 * 128];
  uint8_t* lB = &Bs[wave * 32 * 128];

  const int m0 = (wave >> 1) * 64;
  const int n0 = (wave & 1) * 64;
  const int fr = lane & 15;    // row/col within 16-block
  const int h  = lane >> 4;    // 0..3: k-block of 32 bytes

  f32x4 acc[4][4] = {};

  for (int kt = 0; kt < NKT; ++kt) {
    __syncthreads();  // previous tile fully consumed
    const int kOff = kt * BK;
#pragma unroll
    for (int l = 0; l < 4; ++l)
      GLOAD_LDS16(gA + (size_t)(l * 8) * DIM + kOff, lA + l * 8 * 128);
#pragma unroll
    for (int l = 0; l < 4; ++l)
      GLOAD_LDS16(gB + (size_t)(l * 8) * DIM + kOff, lB + l * 8 * 128);
    __syncthreads();  // vmcnt(0) drain + barrier: tile landed

    // fragments: A[row = m0+mi*16+fr][k = h*32 .. h*32+32) ; 32B = 2 b128
    v8i af[4], bf[4];
#pragma unroll
    for (int mi = 0; mi < 4; ++mi) {
      const int row = m0 + mi * 16 + fr;
      const int r7 = row & 7;
      uint4 lo = *(const uint4*)&As[row * 128 + (((h * 2) ^ r7) * 16)];
      uint4 hi = *(const uint4*)&As[row * 128 + (((h * 2 + 1) ^ r7) * 16)];
      af[mi][0] = (int)lo.x; af[mi][1] = (int)lo.y; af[mi][2] = (int)lo.z; af[mi][3] = (int)lo.w;
      af[mi][4] = (int)hi.x; af[mi][5] = (int)hi.y; af[mi][6] = (int)hi.z; af[mi][7] = (int)hi.w;
    }
#pragma unroll
    for (int ni = 0; ni < 4; ++ni) {
      const int row = n0 + ni * 16 + fr;
      const int r7 = row & 7;
      uint4 lo = *(const uint4*)&Bs[row * 128 + (((h * 2) ^ r7) * 16)];
      uint4 hi = *(const uint4*)&Bs[row * 128 + (((h * 2 + 1) ^ r7) * 16)];
      bf[ni][0] = (int)lo.x; bf[ni][1] = (int)lo.y; bf[ni][2] = (int)lo.z; bf[ni][3] = (int)lo.w;
      bf[ni][4] = (int)hi.x; bf[ni][5] = (int)hi.y; bf[ni][6] = (int)hi.z; bf[ni][7] = (int)hi.w;
    }
#pragma unroll
    for (int mi = 0; mi < 4; ++mi)
#pragma unroll
      for (int ni = 0; ni < 4; ++ni)
        acc[mi][ni] = __builtin_amdgcn_mfma_scale_f32_16x16x128_f8f6f4(
            af[mi], bf[ni], acc[mi][ni],
            0, 0,                      // cbsz=0 (A fp8 e4m3), blgp=0 (B fp8 e4m3)
            0, 0x7F7F7F7F,             // scale A: e8m0 1.0 (opsel 0)
            0, 0x7F7F7F7F);            // scale B: e8m0 1.0
  }

  // epilogue: C/D layout col = lane&15, row = (lane>>4)*4 + reg (shape-determined)
  const int col = lane & 15;
  const int rquad = (lane >> 4) * 4;
  float lsum = 0.0f;
#pragma unroll
  for (int ni = 0; ni < 4; ++ni) {
    const int tj = tCol[n0 + ni * 16 + col];
#pragma unroll
    for (int mi = 0; mi < 4; ++mi) {
#pragma unroll
      for (int r = 0; r < 4; ++r) {
        float s = acc[mi][ni][r];
        int ti = tRow[m0 + mi * 16 + rquad + r];
        lsum += (ti == tj) ? (s < 1.0f ? 1.0f - s : 0.0f)
                           : (s > MARGIN ? s : 0.0f);
      }
    }
  }
  if (bi != bj) lsum *= 2.0f;  // symmetric half counted twice

#pragma unroll
  for (int off = 32; off > 0; off >>= 1) lsum += __shfl_down(lsum, off, 64);
  if (lane == 0) wsum[wave] = lsum;
  __syncthreads();
  if (tid == 0)
    atomicAdd(out, (wsum[0] + wsum[1] + wsum[2] + wsum[3]) * (1.0f / (float)NROWS));
}

extern "C" void kernel_launch(void* const* d_in, const int* in_sizes, int n_in,
                              void* d_out, int out_size, void* d_ws, size_t ws_size,
                              hipStream_t stream) {
  const float* x = (const float*)d_in[0];
  const int* targets = (const int*)d_in[1];
  float* out = (float*)d_out;
  uint8_t* x8 = (uint8_t*)d_ws;  // 8192*1024 = 8 MiB scratch

  cvt_f32_fp8<<<2048, 256, 0, stream>>>(x, x8, out);   // 8388608 = 2048*256*16
  gram_loss<<<2080, 256, 0, stream>>>(x8, targets, out);  // 64*65/2 upper-tri blocks
}

// Round 7
// 233.965 us; speedup vs baseline: 3.3990x; 3.3990x over previous
//
#include <hip/hip_runtime.h>
#include <stdint.h>

typedef int v8i __attribute__((ext_vector_type(8)));
typedef float f32x4 __attribute__((ext_vector_type(4)));

#define NROWS 8192
#define DIM   1024
#define BK    128
#define NKT   (DIM / BK)   // 8
#define MARGIN 0.3f

// async global->LDS, 16B per lane; LDS dest = wave-uniform base + lane*16
#define GLOAD_LDS16(gp, lp)                                                    \
  __builtin_amdgcn_global_load_lds(                                            \
      (const __attribute__((address_space(1))) void*)(gp),                     \
      (__attribute__((address_space(3))) void*)(lp), 16, 0, 0)

// fp32 [8192*1024] -> fp8 e4m3 (OCP, v_cvt_pk_fp8_f32); 16 elems/thread.
// Also zeroes the scalar output.  (verified correct in R6: absmax 0.0)
__global__ __launch_bounds__(256) void cvt_f32_fp8(const float* __restrict__ in,
                                                   uint8_t* __restrict__ out,
                                                   float* __restrict__ loss) {
  if (blockIdx.x == 0 && threadIdx.x == 0) loss[0] = 0.0f;
  size_t i = ((size_t)blockIdx.x * 256 + threadIdx.x) * 16;
  float4 v0 = *(const float4*)(in + i);
  float4 v1 = *(const float4*)(in + i + 4);
  float4 v2 = *(const float4*)(in + i + 8);
  float4 v3 = *(const float4*)(in + i + 12);
  int w0 = 0, w1 = 0, w2 = 0, w3 = 0;
  w0 = __builtin_amdgcn_cvt_pk_fp8_f32(v0.x, v0.y, w0, false);
  w0 = __builtin_amdgcn_cvt_pk_fp8_f32(v0.z, v0.w, w0, true);
  w1 = __builtin_amdgcn_cvt_pk_fp8_f32(v1.x, v1.y, w1, false);
  w1 = __builtin_amdgcn_cvt_pk_fp8_f32(v1.z, v1.w, w1, true);
  w2 = __builtin_amdgcn_cvt_pk_fp8_f32(v2.x, v2.y, w2, false);
  w2 = __builtin_amdgcn_cvt_pk_fp8_f32(v2.z, v2.w, w2, true);
  w3 = __builtin_amdgcn_cvt_pk_fp8_f32(v3.x, v3.y, w3, false);
  w3 = __builtin_amdgcn_cvt_pk_fp8_f32(v3.z, v3.w, w3, true);
  uint4 p; p.x = (unsigned)w0; p.y = (unsigned)w1; p.z = (unsigned)w2; p.w = (unsigned)w3;
  *(uint4*)(out + i) = p;
}

// One block = one 128x128 tile of sim = A*A^T (upper triangle, bi<=bj).
// MX-fp8 (layout verified R6). R7 fixes the R6 spill: no min-waves bound
// (R6's (256,3) capped the unified VGPR+AGPR file at ~170 < the ~170+ needed
// -> 905 MB scratch traffic), plain row-major LDS (R5: banking not a limiter),
// direct 32B vector fragment loads, single live B fragment.
__global__ __launch_bounds__(256) void gram_loss(const uint8_t* __restrict__ A8,
                                                 const int* __restrict__ targets,
                                                 float* __restrict__ out) {
  __shared__ uint8_t As[128 * 128];   // 16 KB, plain row-major [128][128]
  __shared__ uint8_t Bs[128 * 128];   // 16 KB
  __shared__ int tRow[128];
  __shared__ int tCol[128];
  __shared__ float wsum[4];

  // linear block id -> (bi, bj) with 0 <= bi <= bj < 64  (fp32 guess + exact fixup)
  int t = blockIdx.x;
  int bi = (int)(0.5f * (129.0f - __builtin_sqrtf(129.0f * 129.0f - 8.0f * (float)t)));
  if (bi < 0) bi = 0;
  if (bi > 63) bi = 63;
  while (bi < 63 && ((bi + 1) * (129 - (bi + 1))) / 2 <= t) ++bi;
  while (bi > 0 && (bi * (129 - bi)) / 2 > t) --bi;
  int bj = bi + (t - (bi * (129 - bi)) / 2);

  const int iBase = bi * 128;
  const int jBase = bj * 128;

  const int tid  = threadIdx.x;
  const int wave = tid >> 6;
  const int lane = tid & 63;

  if (tid < 128) tRow[tid] = targets[iBase + tid];
  else           tCol[tid - 128] = targets[jBase + tid - 128];

  // staging: wave w stages rows [w*32, w*32+32) of both tiles, 4 loads each.
  // one load = 64 lanes x 16B = 8 rows x 128B; lane -> row offset lane>>3,
  // col-group lane&7 (contiguous, unswizzled).
  const int lrow = lane >> 3;                 // 0..7
  const int cg   = lane & 7;                  // col-group (x16B)
  const uint8_t* gA = A8 + (size_t)(iBase + wave * 32 + lrow) * DIM + cg * 16;
  const uint8_t* gB = A8 + (size_t)(jBase + wave * 32 + lrow) * DIM + cg * 16;
  uint8_t* lA = &As[wave * 32 * 128];
  uint8_t* lB = &Bs[wave * 32 * 128];

  const int m0 = (wave >> 1) * 64;
  const int n0 = (wave & 1) * 64;
  const int fr = lane & 15;    // row within 16-block
  const int h  = lane >> 4;    // 0..3: which 32B k-chunk

  f32x4 acc[4][4] = {};

  for (int kt = 0; kt < NKT; ++kt) {
    __syncthreads();  // previous tile fully consumed
    const int kOff = kt * BK;
#pragma unroll
    for (int l = 0; l < 4; ++l)
      GLOAD_LDS16(gA + (size_t)(l * 8) * DIM + kOff, lA + l * 8 * 128);
#pragma unroll
    for (int l = 0; l < 4; ++l)
      GLOAD_LDS16(gB + (size_t)(l * 8) * DIM + kOff, lB + l * 8 * 128);
    __syncthreads();  // vmcnt(0) drain + barrier: tile landed

    // A fragments: row = m0+mi*16+fr, k-bytes [h*32, h*32+32) — one 32B vec load
    v8i af[4];
#pragma unroll
    for (int mi = 0; mi < 4; ++mi)
      af[mi] = *(const v8i*)&As[(m0 + mi * 16 + fr) * 128 + h * 32];

#pragma unroll
    for (int ni = 0; ni < 4; ++ni) {
      v8i bf = *(const v8i*)&Bs[(n0 + ni * 16 + fr) * 128 + h * 32];
#pragma unroll
      for (int mi = 0; mi < 4; ++mi)
        acc[mi][ni] = __builtin_amdgcn_mfma_scale_f32_16x16x128_f8f6f4(
            af[mi], bf, acc[mi][ni],
            0, 0,                      // cbsz=0 (A fp8 e4m3), blgp=0 (B fp8 e4m3)
            0, 0x7F7F7F7F,             // scale A: e8m0 1.0
            0, 0x7F7F7F7F);            // scale B: e8m0 1.0
    }
  }

  // epilogue: C/D layout col = lane&15, row = (lane>>4)*4 + reg (shape-determined)
  const int col = lane & 15;
  const int rquad = (lane >> 4) * 4;
  float lsum = 0.0f;
#pragma unroll
  for (int ni = 0; ni < 4; ++ni) {
    const int tj = tCol[n0 + ni * 16 + col];
#pragma unroll
    for (int mi = 0; mi < 4; ++mi) {
#pragma unroll
      for (int r = 0; r < 4; ++r) {
        float s = acc[mi][ni][r];
        int ti = tRow[m0 + mi * 16 + rquad + r];
        lsum += (ti == tj) ? (s < 1.0f ? 1.0f - s : 0.0f)
                           : (s > MARGIN ? s : 0.0f);
      }
    }
  }
  if (bi != bj) lsum *= 2.0f;  // symmetric half counted twice

#pragma unroll
  for (int off = 32; off > 0; off >>= 1) lsum += __shfl_down(lsum, off, 64);
  if (lane == 0) wsum[wave] = lsum;
  __syncthreads();
  if (tid == 0)
    atomicAdd(out, (wsum[0] + wsum[1] + wsum[2] + wsum[3]) * (1.0f / (float)NROWS));
}

extern "C" void kernel_launch(void* const* d_in, const int* in_sizes, int n_in,
                              void* d_out, int out_size, void* d_ws, size_t ws_size,
                              hipStream_t stream) {
  const float* x = (const float*)d_in[0];
  const int* targets = (const int*)d_in[1];
  float* out = (float*)d_out;
  uint8_t* x8 = (uint8_t*)d_ws;  // 8192*1024 = 8 MiB scratch

  cvt_f32_fp8<<<2048, 256, 0, stream>>>(x, x8, out);   // 8388608 = 2048*256*16
  gram_loss<<<2080, 256, 0, stream>>>(x8, targets, out);  // 64*65/2 upper-tri blocks
}